// Round 1
// baseline (372.409 us; speedup 1.0000x reference)
//
#include <hip/hip_runtime.h>

// HEALPix pad, p=1, n=128, C=128, B12=24 (B=2 x 12 faces), fp32.
// out[b12, c, r, col] (130x130) from in[b12, c, 128, 128] + neighbor-face halos.
// R3: interior path moves 64B/thread (4x float4, batched loads for MLP),
// nontemporal bulk loads (streaming, working set > L3). Border path unchanged.

#define NPLANE_OUT 16900   // 130*130

__device__ __forceinline__ float hp_face(const float* __restrict__ in, size_t baseoff,
                                         int q, int i, int j) {
  return in[baseoff + ((size_t)q << 21) + (i << 7) + j];
}

__device__ __forceinline__ float hp_val(const float* __restrict__ in, size_t baseoff,
                                        int type, int m, int face, int r, int col) {
  const int L = 127;
  if (r == 0) {
    if (col == 0) {  // TL corner
      if (type == 0) return hp_face(in, baseoff, (m + 2) & 3, 0, 0);
      if (type == 1) return 0.5f * (hp_face(in, baseoff, m, L, 0) +
                                    hp_face(in, baseoff, (m + 3) & 3, 0, L));
      return hp_face(in, baseoff, m, L, L);
    }
    if (col == 129) {  // TR corner
      if (type == 0) return hp_face(in, baseoff, (m + 1) & 3, L, 0);
      if (type == 1) return hp_face(in, baseoff, 4 + ((m + 1) & 3), L, 0);
      return hp_face(in, baseoff, 8 + ((m + 1) & 3), L, 0);
    }
    int j = col - 1;  // top row
    if (type == 0) return hp_face(in, baseoff, (m + 1) & 3, j, 0);
    if (type == 1) return hp_face(in, baseoff, m, L, j);
    return hp_face(in, baseoff, 4 + ((m + 1) & 3), L, j);
  }
  if (r == 129) {
    if (col == 0) {  // BL corner
      if (type == 0) return hp_face(in, baseoff, (m + 3) & 3, 0, L);
      if (type == 1) return hp_face(in, baseoff, 4 + ((m + 3) & 3), 0, L);
      return hp_face(in, baseoff, 8 + ((m + 3) & 3), 0, L);
    }
    if (col == 129) {  // BR corner
      if (type == 0) return hp_face(in, baseoff, 8 + m, 0, 0);
      if (type == 1) return 0.5f * (hp_face(in, baseoff, 8 + ((m + 3) & 3), 0, L) +
                                    hp_face(in, baseoff, 8 + m, L, 0));
      return hp_face(in, baseoff, 8 + ((m + 2) & 3), L, L);
    }
    int j = col - 1;  // bottom row
    if (type == 0) return hp_face(in, baseoff, 4 + m, 0, j);
    if (type == 1) return hp_face(in, baseoff, 8 + ((m + 3) & 3), 0, j);
    return hp_face(in, baseoff, 8 + ((m + 3) & 3), j, L);
  }
  int i = r - 1;
  if (col == 0) {  // left column
    if (type == 0) return hp_face(in, baseoff, (m + 3) & 3, 0, i);
    if (type == 1) return hp_face(in, baseoff, (m + 3) & 3, i, L);
    return hp_face(in, baseoff, 4 + m, i, L);
  }
  // col == 129, right column
  if (type == 0) return hp_face(in, baseoff, 4 + ((m + 1) & 3), i, 0);
  if (type == 1) return hp_face(in, baseoff, 8 + m, i, 0);
  return hp_face(in, baseoff, 8 + ((m + 1) & 3), L, i);
}

typedef float f4v __attribute__((ext_vector_type(4)));
typedef f4v f4u __attribute__((aligned(4)));  // 4B-aligned float4 for unaligned stores

__global__ __launch_bounds__(256) void CREDITHEALPix_90975997264316_kernel(
    const float* __restrict__ in, float* __restrict__ out) {
  int plane = blockIdx.y;      // 0..3071 : b12*128 + c
  int b12 = plane >> 7;
  int c = plane & 127;
  int batch = (b12 >= 12) ? 1 : 0;
  int face = b12 - batch * 12;
  int type = face >> 2;        // 0=north, 1=equatorial, 2=south
  int m = face & 3;
  size_t baseoff = (((size_t)batch * 1536) + (size_t)c) << 14;  // (batch*12*128+c)*16384
  size_t face_off = baseoff + ((size_t)face << 21);
  float* __restrict__ oplane = out + (size_t)plane * NPLANE_OUT;

  if (blockIdx.x < 4) {
    // ---- interior bulk copy: 64B/thread, 4 outstanding loads for MLP ----
    const float* __restrict__ src = in + face_off;
    int q0 = blockIdx.x * 1024 + threadIdx.x;  // quad index base
    f4v v0, v1, v2, v3;
    {
      int q = q0;             // k=0
      v0 = __builtin_nontemporal_load((const f4v*)(src + (size_t)((q >> 5) << 7) + ((q & 31) << 2)));
      q = q0 + 256;           // k=1
      v1 = __builtin_nontemporal_load((const f4v*)(src + (size_t)((q >> 5) << 7) + ((q & 31) << 2)));
      q = q0 + 512;           // k=2
      v2 = __builtin_nontemporal_load((const f4v*)(src + (size_t)((q >> 5) << 7) + ((q & 31) << 2)));
      q = q0 + 768;           // k=3
      v3 = __builtin_nontemporal_load((const f4v*)(src + (size_t)((q >> 5) << 7) + ((q & 31) << 2)));
    }
    {
      int q = q0;
      *(f4u*)(oplane + ((q >> 5) + 1) * 130 + 1 + ((q & 31) << 2)) = v0;
      q = q0 + 256;
      *(f4u*)(oplane + ((q >> 5) + 1) * 130 + 1 + ((q & 31) << 2)) = v1;
      q = q0 + 512;
      *(f4u*)(oplane + ((q >> 5) + 1) * 130 + 1 + ((q & 31) << 2)) = v2;
      q = q0 + 768;
      *(f4u*)(oplane + ((q >> 5) + 1) * 130 + 1 + ((q & 31) << 2)) = v3;
    }
  } else {
    // ---- border: 516 elements per plane ----
    for (int e = threadIdx.x; e < 516; e += 256) {
      int r, col;
      if (e < 130)      { r = 0;       col = e; }
      else if (e < 260) { r = 129;     col = e - 130; }
      else if (e < 388) { r = e - 259; col = 0; }        // rows 1..128, left
      else              { r = e - 387; col = 129; }      // rows 1..128, right
      oplane[r * 130 + col] = hp_val(in, baseoff, type, m, face, r, col);
    }
  }
}

extern "C" void kernel_launch(void* const* d_in, const int* in_sizes, int n_in,
                              void* d_out, int out_size, void* d_ws, size_t ws_size,
                              hipStream_t stream) {
  const float* in = (const float*)d_in[0];
  float* out = (float*)d_out;
  // grid.x: 4 interior blocks (4096 quads, 64B/thread) + 1 border block, per plane
  dim3 grid(5, 3072, 1);
  dim3 block(256, 1, 1);
  CREDITHEALPix_90975997264316_kernel<<<grid, block, 0, stream>>>(in, out);
}